// Round 10
// baseline (171.156 us; speedup 1.0000x reference)
//
#include <hip/hip_runtime.h>

#define BB   32
#define NN   512
#define NH   8
#define FIN  768
#define FHID 64
#define NROWS (BB*NN)   // 16384

typedef __attribute__((ext_vector_type(8))) short bf16x8;
typedef __attribute__((ext_vector_type(4))) short s16x4;
typedef __attribute__((ext_vector_type(4))) float f32x4;
typedef unsigned long long u64;
typedef unsigned short u16;

__device__ __forceinline__ float lrelu_f(float s){ return fmaxf(s, 0.2f*s); }
__device__ __forceinline__ float elu_f(float s){ return s > 0.f ? s : expm1f(s); }
__device__ __forceinline__ short f2bf(float f){
  unsigned u = __float_as_uint(f);
  return (short)((u + 0x7fffu + ((u >> 16) & 1u)) >> 16);   // RNE
}
__device__ __forceinline__ float bf2f(short s){
  return __uint_as_float(((unsigned)(u16)s) << 16);
}
// one instruction converts 2 f32 -> packed 2x bf16 (low=lo, high=hi)
__device__ __forceinline__ unsigned cvt_pk_bf16(float lo, float hi){
  unsigned r;
  asm("v_cvt_pk_bf16_f32 %0, %1, %2" : "=v"(r) : "v"(lo), "v"(hi));
  return r;
}

// ---------------------------------------------------------------------------
// K1a: adjacency -> bitmask words
// ---------------------------------------------------------------------------
__global__ __launch_bounds__(256) void prep_kernel(
    const int* __restrict__ adj,
    u64* __restrict__ maskw)
{
  int row  = blockIdx.x * 4 + (threadIdx.x >> 6);
  int lane = threadIdx.x & 63;
  const int* arow = adj + (long)row * NN;
  #pragma unroll
  for (int w = 0; w < 8; ++w) {
    u64 bal = __ballot(arow[w*64 + lane] > 0);
    if (lane == 0) maskw[(long)row*8 + w] = bal;
  }
}

// ---------------------------------------------------------------------------
// K1b: per-type gathered row lists; 3 global atomics per block.
// ---------------------------------------------------------------------------
__global__ __launch_bounds__(256) void rowlist_kernel(
    const float* __restrict__ vt,
    int* __restrict__ rowlist, int* __restrict__ counts)
{
  __shared__ int lc[3];
  __shared__ int lbase[3];
  int tid = threadIdx.x;
  int row = blockIdx.x * 256 + tid;
  if (tid < 3) lc[tid] = 0;
  __syncthreads();
  const float* v = vt + (long)row*3;
  int t = v[1] > 0.5f ? 1 : (v[2] > 0.5f ? 2 : 0);
  int p = atomicAdd(&lc[t], 1);
  __syncthreads();
  if (tid < 3) lbase[tid] = atomicAdd(&counts[tid], lc[tid]);
  __syncthreads();
  rowlist[t*NROWS + lbase[t] + p] = row;
}

// ---------------------------------------------------------------------------
// K2: weight transpose+cast; blockIdx.y = K-quarter.
// ---------------------------------------------------------------------------
__global__ __launch_bounds__(256) void conv_w(
    const float* __restrict__ w1, const float* __restrict__ w2,
    u16* __restrict__ w1t, u16* __restrict__ w2t)
{
  __shared__ float tile[64][68];
  int bid = blockIdx.x, tid = threadIdx.x;
  const float* src; u16* dst; int K;
  if (bid < 24) { src = w1 + (long)bid*768*64; dst = w1t + (long)bid*64*768; K = 768; }
  else { int t = bid - 24; src = w2 + (long)t*512*64; dst = w2t + (long)t*64*512; K = 512; }
  int kq = blockIdx.y;
  int kstart = kq * (K >> 2), kend = kstart + (K >> 2);

  for (int k0 = kstart; k0 < kend; k0 += 64) {
    __syncthreads();
    #pragma unroll
    for (int i = 0; i < 4; ++i) {
      int kk = i*16 + (tid >> 4);
      int oo = (tid & 15) * 4;
      float4 v = *(const float4*)(src + (long)(k0 + kk)*64 + oo);
      *(float4*)&tile[kk][oo] = v;
    }
    __syncthreads();
    int o = tid >> 2, kp = (tid & 3) * 16;
    bf16x8 r0, r1;
    #pragma unroll
    for (int j = 0; j < 8; ++j) r0[j] = f2bf(tile[kp + j][o]);
    #pragma unroll
    for (int j = 0; j < 8; ++j) r1[j] = f2bf(tile[kp + 8 + j][o]);
    u16* d = dst + (long)o*K + k0 + kp;
    *(bf16x8*)d = r0;
    *(bf16x8*)(d + 8) = r1;
  }
}

// ---------------------------------------------------------------------------
// K3: layer-1 gathered GEMM, bf16 MFMA. (unchanged from round 8)
// ---------------------------------------------------------------------------
__global__ __launch_bounds__(256) void gemm1_mfma(
    const float* __restrict__ emb,
    const u16* __restrict__ w1t,
    const int* __restrict__ rowlist, const int* __restrict__ counts,
    u16* __restrict__ hp1b)
{
  int t   = blockIdx.z;
  int cnt = counts[t];
  int i   = blockIdx.x;
  int xcd = i & 7;
  int q   = i >> 3;
  int hb  = q & 3;
  int rb  = (q >> 2) * 8 + xcd;
  int r0  = rb * 64;
  if (r0 >= cnt) return;

  __shared__ short aT[4*66*8];
  __shared__ short bT[4*130*8];
  __shared__ int rowsS[64];

  int tid = threadIdx.x;
  if (tid < 64) {
    int rr = r0 + tid;
    rowsS[tid] = (rr < cnt) ? rowlist[t*NROWS + rr] : -1;
  }
  __syncthreads();

  int ar = tid >> 2, ac = tid & 3;
  int sg = rowsS[ar]; if (sg < 0) sg = rowsS[0];
  const float* aP = emb + (long)sg*768;

  int colb = tid >> 2, off = tid & 3;
  const u16* bP1 = w1t + (((long)t*8 + hb*2 + 0)*64 + colb)*768;
  const u16* bP2 = w1t + (((long)t*8 + hb*2 + 1)*64 + colb)*768;

  int wv = tid >> 6, l = tid & 63;
  int wr = wv >> 1, wc = wv & 1;
  int l15 = l & 15, lg = l >> 4;

  f32x4 acc[2][4];
  #pragma unroll
  for (int fr = 0; fr < 2; ++fr)
    #pragma unroll
    for (int cf = 0; cf < 4; ++cf) acc[fr][cf] = (f32x4){0.f,0.f,0.f,0.f};

  float4 ra0 = *(const float4*)(aP + ac*4);
  float4 ra1 = *(const float4*)(aP + 16 + ac*4);
  bf16x8 rb1 = *(const bf16x8*)(bP1 + off*8);
  bf16x8 rb2 = *(const bf16x8*)(bP2 + off*8);

  for (int k0 = 0; k0 < 768; k0 += 32) {
    __syncthreads();
    s16x4 w0, w1;
    w0[0]=f2bf(ra0.x); w0[1]=f2bf(ra0.y); w0[2]=f2bf(ra0.z); w0[3]=f2bf(ra0.w);
    w1[0]=f2bf(ra1.x); w1[1]=f2bf(ra1.y); w1[2]=f2bf(ra1.z); w1[3]=f2bf(ra1.w);
    *(s16x4*)&aT[(( (ac>>1)     )*66 + ar)*8 + (ac&1)*4] = w0;
    *(s16x4*)&aT[(( 2 + (ac>>1) )*66 + ar)*8 + (ac&1)*4] = w1;
    *(bf16x8*)&bT[(off*130 + colb     )*8] = rb1;
    *(bf16x8*)&bT[(off*130 + colb + 64)*8] = rb2;
    __syncthreads();
    if (k0 + 32 < 768) {
      ra0 = *(const float4*)(aP + k0 + 32 + ac*4);
      ra1 = *(const float4*)(aP + k0 + 48 + ac*4);
      rb1 = *(const bf16x8*)(bP1 + k0 + 32 + off*8);
      rb2 = *(const bf16x8*)(bP2 + k0 + 32 + off*8);
    }
    bf16x8 af[2], bfr[4];
    #pragma unroll
    for (int fr = 0; fr < 2; ++fr)
      af[fr] = *(const bf16x8*)&aT[(lg*66 + wr*32 + fr*16 + l15)*8];
    #pragma unroll
    for (int cf = 0; cf < 4; ++cf)
      bfr[cf] = *(const bf16x8*)&bT[(lg*130 + wc*64 + cf*16 + l15)*8];
    #pragma unroll
    for (int fr = 0; fr < 2; ++fr)
      #pragma unroll
      for (int cf = 0; cf < 4; ++cf)
        acc[fr][cf] = __builtin_amdgcn_mfma_f32_16x16x32_bf16(af[fr], bfr[cf], acc[fr][cf], 0, 0, 0);
  }

  #pragma unroll
  for (int fr = 0; fr < 2; ++fr) {
    #pragma unroll
    for (int r = 0; r < 4; ++r) {
      int rloc = wr*32 + fr*16 + lg*4 + r;
      int rg = rowsS[rloc];
      if (rg < 0) continue;
      long obase = ((long)(rg >> 9) * 8) * 32768 + (long)(rg & 511) * 64;
      #pragma unroll
      for (int cf = 0; cf < 4; ++cf) {
        int c = wc*64 + cf*16 + l15;
        hp1b[obase + (long)(hb*2 + (c >> 6))*32768 + (c & 63)] = (u16)f2bf(acc[fr][cf][r]);
      }
    }
  }
}

// ---------------------------------------------------------------------------
// K5: layer-2 gathered GEMM, bf16 MFMA. (unchanged)
// ---------------------------------------------------------------------------
__global__ __launch_bounds__(256) void gemm2_mfma(
    const u16* __restrict__ xbf,
    const u16* __restrict__ w2t,
    const int* __restrict__ rowlist, const int* __restrict__ counts,
    float* __restrict__ hp2)
{
  int t   = blockIdx.z;
  int cnt = counts[t];
  int r0  = blockIdx.y * 64;
  if (r0 >= cnt) return;

  __shared__ short aT[4*66*8];
  __shared__ short bT[4*66*8];
  __shared__ int rowsS[64];

  int tid = threadIdx.x;
  if (tid < 64) {
    int rr = r0 + tid;
    rowsS[tid] = (rr < cnt) ? rowlist[t*NROWS + rr] : -1;
  }
  __syncthreads();

  int ar = tid >> 2, ac = tid & 3;
  int sg = rowsS[ar]; if (sg < 0) sg = rowsS[0];
  long apart = ((long)(sg >> 9) * 8) * 32768 + (long)(sg & 511) * 64;

  int colb = tid >> 2, off = tid & 3;
  const u16* bP = w2t + ((long)t*64 + colb)*512;

  int wv = tid >> 6, l = tid & 63;
  int l15 = l & 15, lg = l >> 4;

  f32x4 acc[4];
  #pragma unroll
  for (int cf = 0; cf < 4; ++cf) acc[cf] = (f32x4){0.f,0.f,0.f,0.f};

  int ka0 = ac*8;
  bf16x8 ra = *(const bf16x8*)(xbf + apart + (long)(ka0 >> 6)*32768 + (ka0 & 63));
  bf16x8 rb = *(const bf16x8*)(bP + off*8);

  for (int k0 = 0; k0 < 512; k0 += 32) {
    __syncthreads();
    *(bf16x8*)&aT[(ac*66 + ar)*8]   = ra;
    *(bf16x8*)&bT[(off*66 + colb)*8] = rb;
    __syncthreads();
    if (k0 + 32 < 512) {
      int kn = k0 + 32 + ac*8;
      ra = *(const bf16x8*)(xbf + apart + (long)(kn >> 6)*32768 + (kn & 63));
      rb = *(const bf16x8*)(bP + k0 + 32 + off*8);
    }
    bf16x8 af, bfr[4];
    af = *(const bf16x8*)&aT[(lg*66 + wv*16 + l15)*8];
    #pragma unroll
    for (int cf = 0; cf < 4; ++cf)
      bfr[cf] = *(const bf16x8*)&bT[(lg*66 + cf*16 + l15)*8];
    #pragma unroll
    for (int cf = 0; cf < 4; ++cf)
      acc[cf] = __builtin_amdgcn_mfma_f32_16x16x32_bf16(af, bfr[cf], acc[cf], 0, 0, 0);
  }

  #pragma unroll
  for (int r = 0; r < 4; ++r) {
    int rloc = wv*16 + lg*4 + r;
    int rg = rowsS[rloc];
    if (rg < 0) continue;
    #pragma unroll
    for (int cf = 0; cf < 4; ++cf)
      hp2[(long)rg*64 + cf*16 + l15] = acc[cf][r];
  }
}

// ---------------------------------------------------------------------------
// K4 helpers: softmax of 4 rows -> packed bf16 P in registers (+ rcp write),
// and the register->LDS dump. Layout of pSf unchanged from round 9.
// ---------------------------------------------------------------------------
__device__ __forceinline__ void softmax_rows(
    int b, int sup, int wv, int lane,
    const u64* __restrict__ maskw, const float* srcS, const float (&dstv)[8],
    float* rcpDst, unsigned (&pk)[4][4])
{
  #pragma unroll
  for (int rr = 0; rr < 4; ++rr) {
    int rloc = wv*4 + rr;
    int row  = sup*64 + rloc;
    float srcv = srcS[row];
    const u64* mrow = maskw + ((long)(b*NN + row))*8;
    float ev[8];
    float lsum = 0.f;
    #pragma unroll
    for (int j = 0; j < 8; ++j) {
      u64 w = mrow[j];
      float s = srcv + dstv[j];
      float e = ((w >> lane) & 1ull) ? lrelu_f(s) : -1.0e9f;
      float p = __expf(e);                 // masked -> exactly 0
      lsum += p;
      ev[j] = p;
    }
    #pragma unroll
    for (int mk = 1; mk <= 32; mk <<= 1) lsum += __shfl_xor(lsum, mk);
    if (lane == 0) rcpDst[rloc] = 1.f / lsum;
    #pragma unroll
    for (int qq = 0; qq < 4; ++qq)
      pk[rr][qq] = cvt_pk_bf16(ev[2*qq], ev[2*qq+1]);
  }
}

__device__ __forceinline__ void write_pk(
    short* pSf, int wv, int lk, int ls, const unsigned (&pk)[4][4])
{
  #pragma unroll
  for (int rr = 0; rr < 4; ++rr) {
    int rloc = wv*4 + rr;
    #pragma unroll
    for (int qq = 0; qq < 4; ++qq) {
      unsigned v = pk[rr][qq];
      pSf[(((2*qq    )*8 + lk)*66 + rloc)*8 + ls] = (short)(v & 0xffffu);
      pSf[(((2*qq + 1)*8 + lk)*66 + rloc)*8 + ls] = (short)(v >> 16);
    }
  }
}

// ---------------------------------------------------------------------------
// K4: GAT layer-1 attention. One 1024-thread block per (b,h).
// Round-10: software-pipelined — softmax(sup+1) computes P into REGISTERS
// (cvt_pk bf16 pairs) in the same barrier window as PV(sup)'s MFMAs, so the
// VALU softmax overlaps the matrix/LDS PV (previously strictly serialized by
// barriers; softmax VALU was the binder). dstS hoisted to 8 regs (row-
// invariant). rcpS double-buffered. pSf layout and PV unchanged.
// ---------------------------------------------------------------------------
__global__ __launch_bounds__(1024) void gat1_attn(
    u16* __restrict__ hp1b, const u64* __restrict__ maskw,
    const float* __restrict__ a_src, const float* __restrict__ a_dst,
    const float* __restrict__ b1)
{
  extern __shared__ char smc[];
  short* hpTf = (short*)smc;                  // [64 koct][66 o][8]  67,584 B
  short* pSf  = (short*)(smc + 67584);        // [64 koct][66 row][8] 67,584 B
  float* srcS = (float*)(smc + 135168);       // [512]
  float* dstS = (float*)(smc + 137216);       // [512]
  float* asS  = (float*)(smc + 139264);       // [64]
  float* adS  = (float*)(smc + 139520);       // [64]
  float* rcpS = (float*)(smc + 139776);       // [2][64]  end 140,288

  int bh = blockIdx.x;
  int b = bh >> 3, h = bh & 7;
  int tid = threadIdx.x;

  if (tid < 64) asS[tid] = a_src[h*64 + tid];
  else if (tid < 128) adS[tid - 64] = a_dst[h*64 + (tid - 64)];
  __syncthreads();

  // phase 0: load V slice, src/dst dots, scatter V into fragment order
  {
    int m = tid >> 1, half = tid & 1;
    int koct = m >> 3, sub = m & 7;
    const u16* hpRow = hp1b + ((long)bh*NN + m)*64 + half*32;
    float ps = 0.f, pd = 0.f;
    #pragma unroll
    for (int qq = 0; qq < 4; ++qq) {
      bf16x8 hv = *(const bf16x8*)(hpRow + qq*8);
      int o0 = half*32 + qq*8;
      #pragma unroll
      for (int j = 0; j < 8; ++j) {
        float f = bf2f(hv[j]);
        ps += f * asS[o0 + j];
        pd += f * adS[o0 + j];
        hpTf[(koct*66 + o0 + j)*8 + sub] = hv[j];
      }
    }
    ps += __shfl_xor(ps, 1);
    pd += __shfl_xor(pd, 1);
    if ((tid & 1) == 0) { srcS[m] = ps; dstS[m] = pd; }
  }
  __syncthreads();

  int wv = tid >> 6, lane = tid & 63;
  int l15 = lane & 15, lg = lane >> 4;
  int cgl = wv >> 2, nt = wv & 3;
  int lk = lane >> 3, ls = lane & 7;
  int o_out = nt*16 + l15;
  float bb  = b1[o_out];

  // hoist dst values: row-invariant per lane
  float dstv[8];
  #pragma unroll
  for (int j = 0; j < 8; ++j) dstv[j] = dstS[j*64 + lane];

  // prologue: P(0) -> regs -> LDS
  {
    unsigned pk0[4][4];
    softmax_rows(b, 0, wv, lane, maskw, srcS, dstv, rcpS, pk0);
    write_pk(pSf, wv, lk, ls, pk0);
  }
  __syncthreads();

  for (int sup = 0; sup < 8; ++sup) {
    // softmax(sup+1) into registers — overlaps PV(sup) below (no LDS use)
    unsigned pk2[4][4];
    if (sup < 7)
      softmax_rows(b, sup + 1, wv, lane, maskw, srcS, dstv,
                   rcpS + ((sup + 1) & 1)*64, pk2);

    // PV(sup) via MFMA: wave (cgl,nt) -> rows cgl*16.., cols nt*16.., K=512
    f32x4 acc = {0.f, 0.f, 0.f, 0.f};
    #pragma unroll
    for (int ks = 0; ks < 16; ++ks) {
      int koct = ks*4 + lg;
      bf16x8 af = *(const bf16x8*)&pSf [(koct*66 + cgl*16 + l15)*8];
      bf16x8 bf = *(const bf16x8*)&hpTf[(koct*66 + nt*16  + l15)*8];
      acc = __builtin_amdgcn_mfma_f32_16x16x32_bf16(af, bf, acc, 0, 0, 0);
    }
    const float* rcpCur = rcpS + (sup & 1)*64;
    #pragma unroll
    for (int reg = 0; reg < 4; ++reg) {
      int rloc = cgl*16 + lg*4 + reg;
      int row  = sup*64 + rloc;
      float v = elu_f(acc[reg] * rcpCur[rloc] + bb);
      hp1b[((long)bh*NN + row)*64 + o_out] = (u16)f2bf(v);
    }
    __syncthreads();                 // all PV reads of pSf complete
    if (sup < 7) write_pk(pSf, wv, lk, ls, pk2);
    __syncthreads();                 // P(sup+1) visible
  }
}

// ---------------------------------------------------------------------------
// K6: GAT layer-2 attention (rows 0,1 only) + ELU + MLP + log_softmax.
// ---------------------------------------------------------------------------
__global__ __launch_bounds__(256) void gat2_final(
    const float* __restrict__ hp2, const u64* __restrict__ maskw,
    const float* __restrict__ a_src2, const float* __restrict__ a_dst2,
    const float* __restrict__ b2,
    const float* __restrict__ fc1_w, const float* __restrict__ fc1_b,
    const float* __restrict__ fc2_w, const float* __restrict__ fc2_b,
    const float* __restrict__ fc3_w, const float* __restrict__ fc3_b,
    float* __restrict__ out)
{
  extern __shared__ float sm[];
  float* hpS  = sm;              // 32768
  float* dstS = hpS + 32768;     // 512
  float* srcS = dstS + 512;      // 512
  float* pS   = srcS + 512;      // 512
  float* redS = pS + 512;        // 256
  float* outS = redS + 256;      // 128
  float* vS   = outS + 128;      // 64
  float* y1S  = vS + 64;         // 192
  float* redM = y1S + 192;       // 8
  float4* hpS4 = (float4*)hpS;

  int b = blockIdx.x;
  int tid = threadIdx.x;
  int og = tid & 15, m16 = tid >> 4;

  for (int it = 0; it < 32; ++it) {
    int fi = it*256 + tid;
    int m = fi >> 4, o4 = fi & 15;
    hpS4[m*16 + o4] = *(const float4*)(hp2 + (long)(b*NN + m)*64 + o4*4);
  }
  __syncthreads();

  float4 as4 = *(const float4*)(a_src2 + og*4);
  float4 ad4 = *(const float4*)(a_dst2 + og*4);
  for (int it = 0; it < 32; ++it) {
    int m = it*16 + m16;
    float4 hv = hpS4[m*16 + og];
    float ls = hv.x*as4.x + hv.y*as4.y + hv.z*as4.z + hv.w*as4.w;
    float ld = hv.x*ad4.x + hv.y*ad4.y + hv.z*ad4.z + hv.w*ad4.w;
    #pragma unroll
    for (int mk = 1; mk <= 8; mk <<= 1) {
      ls += __shfl_xor(ls, mk);
      ld += __shfl_xor(ld, mk);
    }
    if (og == 0) { srcS[m] = ls; dstS[m] = ld; }
  }
  __syncthreads();

  for (int n = 0; n < 2; ++n) {
    float srcv = srcS[n];
    const u64* mrow = maskw + (long)(b*NN + n)*8;
    int m0 = tid, m1 = tid + 256;
    u64 w0 = mrow[m0 >> 6], w1 = mrow[m1 >> 6];
    float s0 = srcv + dstS[m0], s1 = srcv + dstS[m1];
    float e0 = ((w0 >> (m0 & 63)) & 1ull) ? lrelu_f(s0) : -1.0e9f;
    float e1 = ((w1 >> (m1 & 63)) & 1ull) ? lrelu_f(s1) : -1.0e9f;
    float emax = fmaxf(e0, e1);
    #pragma unroll
    for (int mk = 1; mk <= 32; mk <<= 1) emax = fmaxf(emax, __shfl_xor(emax, mk));
    if ((tid & 63) == 0) redM[tid >> 6] = emax;
    __syncthreads();
    emax = fmaxf(fmaxf(redM[0], redM[1]), fmaxf(redM[2], redM[3]));
    float p0 = __expf(e0 - emax), p1 = __expf(e1 - emax);
    pS[m0] = p0; pS[m1] = p1;
    float lsum = p0 + p1;
    #pragma unroll
    for (int mk = 1; mk <= 32; mk <<= 1) lsum += __shfl_xor(lsum, mk);
    if ((tid & 63) == 0) redM[4 + (tid >> 6)] = lsum;
    __syncthreads();
    float rcp = 1.f / (redM[4] + redM[5] + redM[6] + redM[7]);

    float4 acc = make_float4(0.f,0.f,0.f,0.f);
    for (int mm = 0; mm < 32; ++mm) {
      int m = mm*16 + m16;
      float4 hv = hpS4[m*16 + og];
      float p = pS[m];
      acc.x += hv.x*p; acc.y += hv.y*p; acc.z += hv.z*p; acc.w += hv.w*p;
    }
    acc.x += __shfl_xor(acc.x, 16); acc.y += __shfl_xor(acc.y, 16);
    acc.z += __shfl_xor(acc.z, 16); acc.w += __shfl_xor(acc.w, 16);
    acc.x += __shfl_xor(acc.x, 32); acc.y += __shfl_xor(acc.y, 32);
    acc.z += __shfl_xor(acc.z, 32); acc.w += __shfl_xor(acc.w, 32);
    __syncthreads();
    if ((tid & 63) < 16) ((float4*)redS)[(tid >> 6)*16 + (tid & 15)] = acc;
    __syncthreads();
    if (tid < 16) {
      float4 s = make_float4(0.f,0.f,0.f,0.f);
      #pragma unroll
      for (int w = 0; w < 4; ++w) {
        float4 v = ((float4*)redS)[w*16 + tid];
        s.x += v.x; s.y += v.y; s.z += v.z; s.w += v.w;
      }
      float4 bv = *(const float4*)(b2 + tid*4);
      outS[n*64 + tid*4 + 0] = elu_f(s.x*rcp + bv.x);
      outS[n*64 + tid*4 + 1] = elu_f(s.y*rcp + bv.y);
      outS[n*64 + tid*4 + 2] = elu_f(s.z*rcp + bv.z);
      outS[n*64 + tid*4 + 3] = elu_f(s.w*rcp + bv.w);
    }
    __syncthreads();
  }

  if (tid < 64) vS[tid] = outS[tid] * outS[64 + tid];
  __syncthreads();
  if (tid < 192) {
    float a = fc1_b[tid];
    for (int o = 0; o < 64; ++o) a += vS[o]*fc1_w[o*192 + tid];
    y1S[tid] = a > 0.f ? a : 0.f;
  }
  __syncthreads();
  if (tid < 64) {
    float a = fc2_b[tid];
    for (int j = 0; j < 192; ++j) a += y1S[j]*fc2_w[j*64 + tid];
    vS[tid] = a > 0.f ? a : 0.f;
  }
  __syncthreads();
  if (tid == 0) {
    float t0 = fc3_b[0], t1 = fc3_b[1];
    for (int k = 0; k < 64; ++k) {
      float y = vS[k];
      t0 += y*fc3_w[k*2 + 0];
      t1 += y*fc3_w[k*2 + 1];
    }
    float mx = fmaxf(t0, t1);
    float lse = mx + logf(__expf(t0 - mx) + __expf(t1 - mx));
    out[b*2 + 0] = t0 - lse;
    out[b*2 + 1] = t1 - lse;
  }
}

// ---------------------------------------------------------------------------
extern "C" void kernel_launch(void* const* d_in, const int* in_sizes, int n_in,
                              void* d_out, int out_size, void* d_ws, size_t ws_size,
                              hipStream_t stream) {
  const float* emb    = (const float*)d_in[0];
  const int*   adj    = (const int*)d_in[1];
  const float* vt     = (const float*)d_in[2];
  const float* w1     = (const float*)d_in[3];
  const float* a_src1 = (const float*)d_in[4];
  const float* a_dst1 = (const float*)d_in[5];
  const float* b1     = (const float*)d_in[6];
  const float* w2     = (const float*)d_in[7];
  const float* a_src2 = (const float*)d_in[8];
  const float* a_dst2 = (const float*)d_in[9];
  const float* b2     = (const float*)d_in[10];
  const float* fc1_w  = (const float*)d_in[11];
  const float* fc1_b  = (const float*)d_in[12];
  const float* fc2_w  = (const float*)d_in[13];
  const float* fc2_b  = (const float*)d_in[14];
  const float* fc3_w  = (const float*)d_in[15];
  const float* fc3_b  = (const float*)d_in[16];

  char* ws = (char*)d_ws;
  int* counts  = (int*)ws;
  int* rowlist = (int*)(ws + 4096);
  u64* maskw   = (u64*)(ws + 204800);
  u16* w1t     = (u16*)(ws + 1310720);
  u16* w2t     = (u16*)(ws + 3670016);
  u16* hp1b    = (u16*)(ws + 3932160);
  float* hp2   = (float*)(ws + 20709376);

  hipMemsetAsync(counts, 0, 16, stream);
  prep_kernel<<<NROWS/4, 256, 0, stream>>>(adj, maskw);
  rowlist_kernel<<<NROWS/256, 256, 0, stream>>>(vt, rowlist, counts);
  conv_w<<<dim3(27, 4), 256, 0, stream>>>(w1, w2, w1t, w2t);

  gemm1_mfma<<<dim3(352, 1, 3), 256, 0, stream>>>(emb, w1t, rowlist, counts, hp1b);

  size_t sm1 = 140288;
  gat1_attn<<<BB*NH, 1024, sm1, stream>>>(hp1b, maskw, a_src1, a_dst1, b1);

  gemm2_mfma<<<dim3(1, 256, 3), 256, 0, stream>>>(hp1b, w2t, rowlist, counts, hp2);

  size_t sm2 = (size_t)(32768 + 512 + 512 + 512 + 256 + 128 + 64 + 192 + 8) * 4;
  gat2_final<<<BB, 256, sm2, stream>>>(hp2, maskw, a_src2, a_dst2, b2,
                                       fc1_w, fc1_b, fc2_w, fc2_b, fc3_w, fc3_b,
                                       (float*)d_out);
}

// Round 11
// 158.613 us; speedup vs baseline: 1.0791x; 1.0791x over previous
//
#include <hip/hip_runtime.h>

#define BB   32
#define NN   512
#define NH   8
#define FIN  768
#define FHID 64
#define NROWS (BB*NN)   // 16384

typedef __attribute__((ext_vector_type(8))) short bf16x8;
typedef __attribute__((ext_vector_type(4))) short s16x4;
typedef __attribute__((ext_vector_type(4))) float f32x4;
typedef unsigned long long u64;
typedef unsigned short u16;

__device__ __forceinline__ float lrelu_f(float s){ return fmaxf(s, 0.2f*s); }
__device__ __forceinline__ float elu_f(float s){ return s > 0.f ? s : expm1f(s); }
__device__ __forceinline__ short f2bf(float f){
  unsigned u = __float_as_uint(f);
  return (short)((u + 0x7fffu + ((u >> 16) & 1u)) >> 16);   // RNE
}
__device__ __forceinline__ float bf2f(short s){
  return __uint_as_float(((unsigned)(u16)s) << 16);
}

// ---------------------------------------------------------------------------
// K1a: adjacency -> bitmask words
// ---------------------------------------------------------------------------
__global__ __launch_bounds__(256) void prep_kernel(
    const int* __restrict__ adj,
    u64* __restrict__ maskw)
{
  int row  = blockIdx.x * 4 + (threadIdx.x >> 6);
  int lane = threadIdx.x & 63;
  const int* arow = adj + (long)row * NN;
  #pragma unroll
  for (int w = 0; w < 8; ++w) {
    u64 bal = __ballot(arow[w*64 + lane] > 0);
    if (lane == 0) maskw[(long)row*8 + w] = bal;
  }
}

// ---------------------------------------------------------------------------
// K1b: per-type gathered row lists; 3 global atomics per block.
// ---------------------------------------------------------------------------
__global__ __launch_bounds__(256) void rowlist_kernel(
    const float* __restrict__ vt,
    int* __restrict__ rowlist, int* __restrict__ counts)
{
  __shared__ int lc[3];
  __shared__ int lbase[3];
  int tid = threadIdx.x;
  int row = blockIdx.x * 256 + tid;
  if (tid < 3) lc[tid] = 0;
  __syncthreads();
  const float* v = vt + (long)row*3;
  int t = v[1] > 0.5f ? 1 : (v[2] > 0.5f ? 2 : 0);
  int p = atomicAdd(&lc[t], 1);
  __syncthreads();
  if (tid < 3) lbase[tid] = atomicAdd(&counts[tid], lc[tid]);
  __syncthreads();
  rowlist[t*NROWS + lbase[t] + p] = row;
}

// ---------------------------------------------------------------------------
// K2: weight transpose+cast; blockIdx.y = K-quarter.
// ---------------------------------------------------------------------------
__global__ __launch_bounds__(256) void conv_w(
    const float* __restrict__ w1, const float* __restrict__ w2,
    u16* __restrict__ w1t, u16* __restrict__ w2t)
{
  __shared__ float tile[64][68];
  int bid = blockIdx.x, tid = threadIdx.x;
  const float* src; u16* dst; int K;
  if (bid < 24) { src = w1 + (long)bid*768*64; dst = w1t + (long)bid*64*768; K = 768; }
  else { int t = bid - 24; src = w2 + (long)t*512*64; dst = w2t + (long)t*64*512; K = 512; }
  int kq = blockIdx.y;
  int kstart = kq * (K >> 2), kend = kstart + (K >> 2);

  for (int k0 = kstart; k0 < kend; k0 += 64) {
    __syncthreads();
    #pragma unroll
    for (int i = 0; i < 4; ++i) {
      int kk = i*16 + (tid >> 4);
      int oo = (tid & 15) * 4;
      float4 v = *(const float4*)(src + (long)(k0 + kk)*64 + oo);
      *(float4*)&tile[kk][oo] = v;
    }
    __syncthreads();
    int o = tid >> 2, kp = (tid & 3) * 16;
    bf16x8 r0, r1;
    #pragma unroll
    for (int j = 0; j < 8; ++j) r0[j] = f2bf(tile[kp + j][o]);
    #pragma unroll
    for (int j = 0; j < 8; ++j) r1[j] = f2bf(tile[kp + 8 + j][o]);
    u16* d = dst + (long)o*K + k0 + kp;
    *(bf16x8*)d = r0;
    *(bf16x8*)(d + 8) = r1;
  }
}

// ---------------------------------------------------------------------------
// K3: layer-1 gathered GEMM, bf16 MFMA. BM=64, BN=128, 4 waves (32x64 tile).
// Round-11: DOUBLE-BUFFERED LDS staging, ONE barrier per K-step (was 2):
// compute tile k from buf[cur] while converting/writing tile k+1 into
// buf[cur^1]; end-of-iter barrier both publishes the writes and protects
// the next overwrite. Coalesced staging + XCD-locality decode kept.
// ---------------------------------------------------------------------------
__global__ __launch_bounds__(256) void gemm1_mfma(
    const float* __restrict__ emb,
    const u16* __restrict__ w1t,
    const int* __restrict__ rowlist, const int* __restrict__ counts,
    u16* __restrict__ hp1b)
{
  int t   = blockIdx.z;
  int cnt = counts[t];
  int i   = blockIdx.x;
  int xcd = i & 7;
  int q   = i >> 3;
  int hb  = q & 3;
  int rb  = (q >> 2) * 8 + xcd;
  int r0  = rb * 64;
  if (r0 >= cnt) return;

  __shared__ short aT[2][4*66*8];       // 2 x 4.2 KB
  __shared__ short bT[2][4*130*8];      // 2 x 8.3 KB
  __shared__ int rowsS[64];

  int tid = threadIdx.x;
  if (tid < 64) {
    int rr = r0 + tid;
    rowsS[tid] = (rr < cnt) ? rowlist[t*NROWS + rr] : -1;
  }
  __syncthreads();

  int ar = tid >> 2, ac = tid & 3;
  int sg = rowsS[ar]; if (sg < 0) sg = rowsS[0];
  const float* aP = emb + (long)sg*768;

  int colb = tid >> 2, off = tid & 3;
  const u16* bP1 = w1t + (((long)t*8 + hb*2 + 0)*64 + colb)*768;
  const u16* bP2 = w1t + (((long)t*8 + hb*2 + 1)*64 + colb)*768;

  int wv = tid >> 6, l = tid & 63;
  int wr = wv >> 1, wc = wv & 1;
  int l15 = l & 15, lg = l >> 4;

  // staging-write LDS offsets (within a buffer), in shorts
  int aw0 = (( (ac>>1)     )*66 + ar)*8 + (ac&1)*4;
  int aw1 = (( 2 + (ac>>1) )*66 + ar)*8 + (ac&1)*4;
  int bw0 = (off*130 + colb     )*8;
  int bw1 = (off*130 + colb + 64)*8;

  f32x4 acc[2][4];
  #pragma unroll
  for (int fr = 0; fr < 2; ++fr)
    #pragma unroll
    for (int cf = 0; cf < 4; ++cf) acc[fr][cf] = (f32x4){0.f,0.f,0.f,0.f};

  // preload tile 0 into regs, write buffer 0
  float4 ra0 = *(const float4*)(aP + ac*4);
  float4 ra1 = *(const float4*)(aP + 16 + ac*4);
  bf16x8 rb1 = *(const bf16x8*)(bP1 + off*8);
  bf16x8 rb2 = *(const bf16x8*)(bP2 + off*8);
  {
    s16x4 w0, w1;
    w0[0]=f2bf(ra0.x); w0[1]=f2bf(ra0.y); w0[2]=f2bf(ra0.z); w0[3]=f2bf(ra0.w);
    w1[0]=f2bf(ra1.x); w1[1]=f2bf(ra1.y); w1[2]=f2bf(ra1.z); w1[3]=f2bf(ra1.w);
    *(s16x4*)&aT[0][aw0] = w0;
    *(s16x4*)&aT[0][aw1] = w1;
    *(bf16x8*)&bT[0][bw0] = rb1;
    *(bf16x8*)&bT[0][bw1] = rb2;
  }
  __syncthreads();

  int cur = 0;
  for (int k0 = 0; k0 < 768; k0 += 32) {
    bool more = (k0 + 32 < 768);
    if (more) {                                // issue next-tile loads early
      ra0 = *(const float4*)(aP + k0 + 32 + ac*4);
      ra1 = *(const float4*)(aP + k0 + 48 + ac*4);
      rb1 = *(const bf16x8*)(bP1 + k0 + 32 + off*8);
      rb2 = *(const bf16x8*)(bP2 + k0 + 32 + off*8);
    }
    // compute tile k0 from buf[cur]
    bf16x8 af[2], bfr[4];
    #pragma unroll
    for (int fr = 0; fr < 2; ++fr)
      af[fr] = *(const bf16x8*)&aT[cur][(lg*66 + wr*32 + fr*16 + l15)*8];
    #pragma unroll
    for (int cf = 0; cf < 4; ++cf)
      bfr[cf] = *(const bf16x8*)&bT[cur][(lg*130 + wc*64 + cf*16 + l15)*8];
    #pragma unroll
    for (int fr = 0; fr < 2; ++fr)
      #pragma unroll
      for (int cf = 0; cf < 4; ++cf)
        acc[fr][cf] = __builtin_amdgcn_mfma_f32_16x16x32_bf16(af[fr], bfr[cf], acc[fr][cf], 0, 0, 0);
    // write tile k0+32 into buf[cur^1] (overlaps other waves' compute)
    if (more) {
      s16x4 w0, w1;
      w0[0]=f2bf(ra0.x); w0[1]=f2bf(ra0.y); w0[2]=f2bf(ra0.z); w0[3]=f2bf(ra0.w);
      w1[0]=f2bf(ra1.x); w1[1]=f2bf(ra1.y); w1[2]=f2bf(ra1.z); w1[3]=f2bf(ra1.w);
      *(s16x4*)&aT[cur^1][aw0] = w0;
      *(s16x4*)&aT[cur^1][aw1] = w1;
      *(bf16x8*)&bT[cur^1][bw0] = rb1;
      *(bf16x8*)&bT[cur^1][bw1] = rb2;
    }
    __syncthreads();
    cur ^= 1;
  }

  #pragma unroll
  for (int fr = 0; fr < 2; ++fr) {
    #pragma unroll
    for (int r = 0; r < 4; ++r) {
      int rloc = wr*32 + fr*16 + lg*4 + r;
      int rg = rowsS[rloc];
      if (rg < 0) continue;
      long obase = ((long)(rg >> 9) * 8) * 32768 + (long)(rg & 511) * 64;
      #pragma unroll
      for (int cf = 0; cf < 4; ++cf) {
        int c = wc*64 + cf*16 + l15;
        hp1b[obase + (long)(hb*2 + (c >> 6))*32768 + (c & 63)] = (u16)f2bf(acc[fr][cf][r]);
      }
    }
  }
}

// ---------------------------------------------------------------------------
// K5: layer-2 gathered GEMM, bf16 MFMA. BM=64, BN=64. (unchanged)
// ---------------------------------------------------------------------------
__global__ __launch_bounds__(256) void gemm2_mfma(
    const u16* __restrict__ xbf,
    const u16* __restrict__ w2t,
    const int* __restrict__ rowlist, const int* __restrict__ counts,
    float* __restrict__ hp2)
{
  int t   = blockIdx.z;
  int cnt = counts[t];
  int r0  = blockIdx.y * 64;
  if (r0 >= cnt) return;

  __shared__ short aT[4*66*8];
  __shared__ short bT[4*66*8];
  __shared__ int rowsS[64];

  int tid = threadIdx.x;
  if (tid < 64) {
    int rr = r0 + tid;
    rowsS[tid] = (rr < cnt) ? rowlist[t*NROWS + rr] : -1;
  }
  __syncthreads();

  int ar = tid >> 2, ac = tid & 3;
  int sg = rowsS[ar]; if (sg < 0) sg = rowsS[0];
  long apart = ((long)(sg >> 9) * 8) * 32768 + (long)(sg & 511) * 64;

  int colb = tid >> 2, off = tid & 3;
  const u16* bP = w2t + ((long)t*64 + colb)*512;

  int wv = tid >> 6, l = tid & 63;
  int l15 = l & 15, lg = l >> 4;

  f32x4 acc[4];
  #pragma unroll
  for (int cf = 0; cf < 4; ++cf) acc[cf] = (f32x4){0.f,0.f,0.f,0.f};

  int ka0 = ac*8;
  bf16x8 ra = *(const bf16x8*)(xbf + apart + (long)(ka0 >> 6)*32768 + (ka0 & 63));
  bf16x8 rb = *(const bf16x8*)(bP + off*8);

  for (int k0 = 0; k0 < 512; k0 += 32) {
    __syncthreads();
    *(bf16x8*)&aT[(ac*66 + ar)*8]   = ra;
    *(bf16x8*)&bT[(off*66 + colb)*8] = rb;
    __syncthreads();
    if (k0 + 32 < 512) {
      int kn = k0 + 32 + ac*8;
      ra = *(const bf16x8*)(xbf + apart + (long)(kn >> 6)*32768 + (kn & 63));
      rb = *(const bf16x8*)(bP + k0 + 32 + off*8);
    }
    bf16x8 af, bfr[4];
    af = *(const bf16x8*)&aT[(lg*66 + wv*16 + l15)*8];
    #pragma unroll
    for (int cf = 0; cf < 4; ++cf)
      bfr[cf] = *(const bf16x8*)&bT[(lg*66 + cf*16 + l15)*8];
    #pragma unroll
    for (int cf = 0; cf < 4; ++cf)
      acc[cf] = __builtin_amdgcn_mfma_f32_16x16x32_bf16(af, bfr[cf], acc[cf], 0, 0, 0);
  }

  #pragma unroll
  for (int r = 0; r < 4; ++r) {
    int rloc = wv*16 + lg*4 + r;
    int rg = rowsS[rloc];
    if (rg < 0) continue;
    #pragma unroll
    for (int cf = 0; cf < 4; ++cf)
      hp2[(long)rg*64 + cf*16 + l15] = acc[cf][r];
  }
}

// ---------------------------------------------------------------------------
// K4: GAT layer-1 attention. One 1024-thread block per (b,h).
// Round-9 version (REVERTED from round-10 pipelining, which regressed:
// the reg->LDS dump window serialized and +16 VGPR hurt; VALUBusy 46->37).
// No-max softmax (scores O(5), masked exp(-1e9)=0), unnormalized P written
// immediately, rcp consumed at PV epilogue.
// ---------------------------------------------------------------------------
__global__ __launch_bounds__(1024) void gat1_attn(
    u16* __restrict__ hp1b, const u64* __restrict__ maskw,
    const float* __restrict__ a_src, const float* __restrict__ a_dst,
    const float* __restrict__ b1)
{
  extern __shared__ char smc[];
  short* hpTf = (short*)smc;                  // [64 koct][66 o][8]  67,584 B
  short* pSf  = (short*)(smc + 67584);        // [64 koct][66 row][8] 67,584 B
  float* srcS = (float*)(smc + 135168);       // [512]
  float* dstS = (float*)(smc + 137216);       // [512]
  float* asS  = (float*)(smc + 139264);       // [64]
  float* adS  = (float*)(smc + 139520);       // [64]
  float* rcpS = (float*)(smc + 139776);       // [64]  end 140,032

  int bh = blockIdx.x;
  int b = bh >> 3, h = bh & 7;
  int tid = threadIdx.x;

  if (tid < 64) asS[tid] = a_src[h*64 + tid];
  else if (tid < 128) adS[tid - 64] = a_dst[h*64 + (tid - 64)];
  __syncthreads();

  // phase 0: load V slice, src/dst dots, scatter V into fragment order
  {
    int m = tid >> 1, half = tid & 1;
    int koct = m >> 3, sub = m & 7;
    const u16* hpRow = hp1b + ((long)bh*NN + m)*64 + half*32;
    float ps = 0.f, pd = 0.f;
    #pragma unroll
    for (int qq = 0; qq < 4; ++qq) {
      bf16x8 hv = *(const bf16x8*)(hpRow + qq*8);
      int o0 = half*32 + qq*8;
      #pragma unroll
      for (int j = 0; j < 8; ++j) {
        float f = bf2f(hv[j]);
        ps += f * asS[o0 + j];
        pd += f * adS[o0 + j];
        hpTf[(koct*66 + o0 + j)*8 + sub] = hv[j];
      }
    }
    ps += __shfl_xor(ps, 1);
    pd += __shfl_xor(pd, 1);
    if ((tid & 1) == 0) { srcS[m] = ps; dstS[m] = pd; }
  }
  __syncthreads();

  int wv = tid >> 6, lane = tid & 63;
  int l15 = lane & 15, lg = lane >> 4;
  int cgl = wv >> 2, nt = wv & 3;
  int lk = lane >> 3, ls = lane & 7;
  int o_out = nt*16 + l15;
  float bb  = b1[o_out];

  for (int sup = 0; sup < 8; ++sup) {
    // softmax (no-max, unnormalized): wave wv owns rows sup*64 + wv*4 + {0..3}
    #pragma unroll
    for (int rr = 0; rr < 4; ++rr) {
      int rloc = wv*4 + rr;
      int row  = sup*64 + rloc;
      float srcv = srcS[row];
      const u64* mrow = maskw + ((long)(b*NN + row))*8;
      float lsum = 0.f;
      #pragma unroll
      for (int j = 0; j < 8; ++j) {
        u64 w = mrow[j];
        float s = srcv + dstS[j*64 + lane];
        float e = ((w >> lane) & 1ull) ? lrelu_f(s) : -1.0e9f;
        float p = __expf(e);                        // masked -> exactly 0
        lsum += p;
        pSf[((j*8 + lk)*66 + rloc)*8 + ls] = f2bf(p);   // no sum dependence
      }
      #pragma unroll
      for (int mk = 1; mk <= 32; mk <<= 1) lsum += __shfl_xor(lsum, mk);
      if (lane == 0) rcpS[rloc] = 1.f / lsum;       // consumed at PV epilogue
    }
    __syncthreads();

    // PV via MFMA: wave (cgl,nt) -> rows cgl*16.., cols nt*16.., K=512
    f32x4 acc = {0.f, 0.f, 0.f, 0.f};
    #pragma unroll
    for (int ks = 0; ks < 16; ++ks) {
      int koct = ks*4 + lg;
      bf16x8 af = *(const bf16x8*)&pSf [(koct*66 + cgl*16 + l15)*8];
      bf16x8 bf = *(const bf16x8*)&hpTf[(koct*66 + nt*16  + l15)*8];
      acc = __builtin_amdgcn_mfma_f32_16x16x32_bf16(af, bf, acc, 0, 0, 0);
    }
    #pragma unroll
    for (int reg = 0; reg < 4; ++reg) {
      int rloc = cgl*16 + lg*4 + reg;
      int row  = sup*64 + rloc;
      float v = elu_f(acc[reg] * rcpS[rloc] + bb);  // deferred normalization
      hp1b[((long)bh*NN + row)*64 + o_out] = (u16)f2bf(v);
    }
    __syncthreads();
  }
}

// ---------------------------------------------------------------------------
// K6: GAT layer-2 attention (rows 0,1 only) + ELU + MLP + log_softmax.
// ---------------------------------------------------------------------------
__global__ __launch_bounds__(256) void gat2_final(
    const float* __restrict__ hp2, const u64* __restrict__ maskw,
    const float* __restrict__ a_src2, const float* __restrict__ a_dst2,
    const float* __restrict__ b2,
    const float* __restrict__ fc1_w, const float* __restrict__ fc1_b,
    const float* __restrict__ fc2_w, const float* __restrict__ fc2_b,
    const float* __restrict__ fc3_w, const float* __restrict__ fc3_b,
    float* __restrict__ out)
{
  extern __shared__ float sm[];
  float* hpS  = sm;              // 32768
  float* dstS = hpS + 32768;     // 512
  float* srcS = dstS + 512;      // 512
  float* pS   = srcS + 512;      // 512
  float* redS = pS + 512;        // 256
  float* outS = redS + 256;      // 128
  float* vS   = outS + 128;      // 64
  float* y1S  = vS + 64;         // 192
  float* redM = y1S + 192;       // 8
  float4* hpS4 = (float4*)hpS;

  int b = blockIdx.x;
  int tid = threadIdx.x;
  int og = tid & 15, m16 = tid >> 4;

  for (int it = 0; it < 32; ++it) {
    int fi = it*256 + tid;
    int m = fi >> 4, o4 = fi & 15;
    hpS4[m*16 + o4] = *(const float4*)(hp2 + (long)(b*NN + m)*64 + o4*4);
  }
  __syncthreads();

  float4 as4 = *(const float4*)(a_src2 + og*4);
  float4 ad4 = *(const float4*)(a_dst2 + og*4);
  for (int it = 0; it < 32; ++it) {
    int m = it*16 + m16;
    float4 hv = hpS4[m*16 + og];
    float ls = hv.x*as4.x + hv.y*as4.y + hv.z*as4.z + hv.w*as4.w;
    float ld = hv.x*ad4.x + hv.y*ad4.y + hv.z*ad4.z + hv.w*ad4.w;
    #pragma unroll
    for (int mk = 1; mk <= 8; mk <<= 1) {
      ls += __shfl_xor(ls, mk);
      ld += __shfl_xor(ld, mk);
    }
    if (og == 0) { srcS[m] = ls; dstS[m] = ld; }
  }
  __syncthreads();

  for (int n = 0; n < 2; ++n) {
    float srcv = srcS[n];
    const u64* mrow = maskw + (long)(b*NN + n)*8;
    int m0 = tid, m1 = tid + 256;
    u64 w0 = mrow[m0 >> 6], w1 = mrow[m1 >> 6];
    float s0 = srcv + dstS[m0], s1 = srcv + dstS[m1];
    float e0 = ((w0 >> (m0 & 63)) & 1ull) ? lrelu_f(s0) : -1.0e9f;
    float e1 = ((w1 >> (m1 & 63)) & 1ull) ? lrelu_f(s1) : -1.0e9f;
    float emax = fmaxf(e0, e1);
    #pragma unroll
    for (int mk = 1; mk <= 32; mk <<= 1) emax = fmaxf(emax, __shfl_xor(emax, mk));
    if ((tid & 63) == 0) redM[tid >> 6] = emax;
    __syncthreads();
    emax = fmaxf(fmaxf(redM[0], redM[1]), fmaxf(redM[2], redM[3]));
    float p0 = __expf(e0 - emax), p1 = __expf(e1 - emax);
    pS[m0] = p0; pS[m1] = p1;
    float lsum = p0 + p1;
    #pragma unroll
    for (int mk = 1; mk <= 32; mk <<= 1) lsum += __shfl_xor(lsum, mk);
    if ((tid & 63) == 0) redM[4 + (tid >> 6)] = lsum;
    __syncthreads();
    float rcp = 1.f / (redM[4] + redM[5] + redM[6] + redM[7]);

    float4 acc = make_float4(0.f,0.f,0.f,0.f);
    for (int mm = 0; mm < 32; ++mm) {
      int m = mm*16 + m16;
      float4 hv = hpS4[m*16 + og];
      float p = pS[m];
      acc.x += hv.x*p; acc.y += hv.y*p; acc.z += hv.z*p; acc.w += hv.w*p;
    }
    acc.x += __shfl_xor(acc.x, 16); acc.y += __shfl_xor(acc.y, 16);
    acc.z += __shfl_xor(acc.z, 16); acc.w += __shfl_xor(acc.w, 16);
    acc.x += __shfl_xor(acc.x, 32); acc.y += __shfl_xor(acc.y, 32);
    acc.z += __shfl_xor(acc.z, 32); acc.w += __shfl_xor(acc.w, 32);
    __syncthreads();
    if ((tid & 63) < 16) ((float4*)redS)[(tid >> 6)*16 + (tid & 15)] = acc;
    __syncthreads();
    if (tid < 16) {
      float4 s = make_float4(0.f,0.f,0.f,0.f);
      #pragma unroll
      for (int w = 0; w < 4; ++w) {
        float4 v = ((float4*)redS)[w*16 + tid];
        s.x += v.x; s.y += v.y; s.z += v.z; s.w += v.w;
      }
      float4 bv = *(const float4*)(b2 + tid*4);
      outS[n*64 + tid*4 + 0] = elu_f(s.x*rcp + bv.x);
      outS[n*64 + tid*4 + 1] = elu_f(s.y*rcp + bv.y);
      outS[n*64 + tid*4 + 2] = elu_f(s.z*rcp + bv.z);
      outS[n*64 + tid*4 + 3] = elu_f(s.w*rcp + bv.w);
    }
    __syncthreads();
  }

  if (tid < 64) vS[tid] = outS[tid] * outS[64 + tid];
  __syncthreads();
  if (tid < 192) {
    float a = fc1_b[tid];
    for (int o = 0; o < 64; ++o) a += vS[o]*fc1_w[o*192 + tid];
    y1S[tid] = a > 0.f ? a : 0.f;
  }
  __syncthreads();
  if (tid < 64) {
    float a = fc2_b[tid];
    for (int j = 0; j < 192; ++j) a += y1S[j]*fc2_w[j*64 + tid];
    vS[tid] = a > 0.f ? a : 0.f;
  }
  __syncthreads();
  if (tid == 0) {
    float t0 = fc3_b[0], t1 = fc3_b[1];
    for (int k = 0; k < 64; ++k) {
      float y = vS[k];
      t0 += y*fc3_w[k*2 + 0];
      t1 += y*fc3_w[k*2 + 1];
    }
    float mx = fmaxf(t0, t1);
    float lse = mx + logf(__expf(t0 - mx) + __expf(t1 - mx));
    out[b*2 + 0] = t0 - lse;
    out[b*2 + 1] = t1 - lse;
  }
}

// ---------------------------------------------------------------------------
extern "C" void kernel_launch(void* const* d_in, const int* in_sizes, int n_in,
                              void* d_out, int out_size, void* d_ws, size_t ws_size,
                              hipStream_t stream) {
  const float* emb    = (const float*)d_in[0];
  const int*   adj    = (const int*)d_in[1];
  const float* vt     = (const float*)d_in[2];
  const float* w1     = (const float*)d_in[3];
  const float* a_src1 = (const float*)d_in[4];
  const float* a_dst1 = (const float*)d_in[5];
  const float* b1     = (const float*)d_in[6];
  const float* w2     = (const float*)d_in[7];
  const float* a_src2 = (const float*)d_in[8];
  const float* a_dst2 = (const float*)d_in[9];
  const float* b2     = (const float*)d_in[10];
  const float* fc1_w  = (const float*)d_in[11];
  const float* fc1_b  = (const float*)d_in[12];
  const float* fc2_w  = (const float*)d_in[13];
  const float* fc2_b  = (const float*)d_in[14];
  const float* fc3_w  = (const float*)d_in[15];
  const float* fc3_b  = (const float*)d_in[16];

  char* ws = (char*)d_ws;
  int* counts  = (int*)ws;
  int* rowlist = (int*)(ws + 4096);
  u64* maskw   = (u64*)(ws + 204800);
  u16* w1t     = (u16*)(ws + 1310720);
  u16* w2t     = (u16*)(ws + 3670016);
  u16* hp1b    = (u16*)(ws + 3932160);
  float* hp2   = (float*)(ws + 20709376);

  hipMemsetAsync(counts, 0, 16, stream);
  prep_kernel<<<NROWS/4, 256, 0, stream>>>(adj, maskw);
  rowlist_kernel<<<NROWS/256, 256, 0, stream>>>(vt, rowlist, counts);
  conv_w<<<dim3(27, 4), 256, 0, stream>>>(w1, w2, w1t, w2t);

  gemm1_mfma<<<dim3(352, 1, 3), 256, 0, stream>>>(emb, w1t, rowlist, counts, hp1b);

  size_t sm1 = 140032;
  gat1_attn<<<BB*NH, 1024, sm1, stream>>>(hp1b, maskw, a_src1, a_dst1, b1);

  gemm2_mfma<<<dim3(1, 256, 3), 256, 0, stream>>>(hp1b, w2t, rowlist, counts, hp2);

  size_t sm2 = (size_t)(32768 + 512 + 512 + 512 + 256 + 128 + 64 + 192 + 8) * 4;
  gat2_final<<<BB, 256, sm2, stream>>>(hp2, maskw, a_src2, a_dst2, b2,
                                       fc1_w, fc1_b, fc2_w, fc2_b, fc3_w, fc3_b,
                                       (float*)d_out);
}

// Round 12
// 147.148 us; speedup vs baseline: 1.1632x; 1.0779x over previous
//
#include <hip/hip_runtime.h>

#define BB   32
#define NN   512
#define NH   8
#define FIN  768
#define FHID 64
#define NROWS (BB*NN)   // 16384

typedef __attribute__((ext_vector_type(8))) short bf16x8;
typedef __attribute__((ext_vector_type(4))) short s16x4;
typedef __attribute__((ext_vector_type(4))) float f32x4;
typedef unsigned long long u64;
typedef unsigned short u16;

__device__ __forceinline__ float lrelu_f(float s){ return fmaxf(s, 0.2f*s); }
__device__ __forceinline__ float elu_f(float s){ return s > 0.f ? s : expm1f(s); }
__device__ __forceinline__ short f2bf(float f){
  unsigned u = __float_as_uint(f);
  return (short)((u + 0x7fffu + ((u >> 16) & 1u)) >> 16);   // RNE
}
__device__ __forceinline__ float bf2f(short s){
  return __uint_as_float(((unsigned)(u16)s) << 16);
}
// one instruction: packed {bf16(lo), bf16(hi)} in one u32
__device__ __forceinline__ unsigned cvt_pk_bf16(float lo, float hi){
  unsigned r;
  asm("v_cvt_pk_bf16_f32 %0, %1, %2" : "=v"(r) : "v"(lo), "v"(hi));
  return r;
}

// ---------------------------------------------------------------------------
// K1a: adjacency -> bitmask words
// ---------------------------------------------------------------------------
__global__ __launch_bounds__(256) void prep_kernel(
    const int* __restrict__ adj,
    u64* __restrict__ maskw)
{
  int row  = blockIdx.x * 4 + (threadIdx.x >> 6);
  int lane = threadIdx.x & 63;
  const int* arow = adj + (long)row * NN;
  #pragma unroll
  for (int w = 0; w < 8; ++w) {
    u64 bal = __ballot(arow[w*64 + lane] > 0);
    if (lane == 0) maskw[(long)row*8 + w] = bal;
  }
}

// ---------------------------------------------------------------------------
// K1b: per-type gathered row lists; 3 global atomics per block.
// ---------------------------------------------------------------------------
__global__ __launch_bounds__(256) void rowlist_kernel(
    const float* __restrict__ vt,
    int* __restrict__ rowlist, int* __restrict__ counts)
{
  __shared__ int lc[3];
  __shared__ int lbase[3];
  int tid = threadIdx.x;
  int row = blockIdx.x * 256 + tid;
  if (tid < 3) lc[tid] = 0;
  __syncthreads();
  const float* v = vt + (long)row*3;
  int t = v[1] > 0.5f ? 1 : (v[2] > 0.5f ? 2 : 0);
  int p = atomicAdd(&lc[t], 1);
  __syncthreads();
  if (tid < 3) lbase[tid] = atomicAdd(&counts[tid], lc[tid]);
  __syncthreads();
  rowlist[t*NROWS + lbase[t] + p] = row;
}

// ---------------------------------------------------------------------------
// K2: weight transpose+cast; blockIdx.y = K-quarter.
// ---------------------------------------------------------------------------
__global__ __launch_bounds__(256) void conv_w(
    const float* __restrict__ w1, const float* __restrict__ w2,
    u16* __restrict__ w1t, u16* __restrict__ w2t)
{
  __shared__ float tile[64][68];
  int bid = blockIdx.x, tid = threadIdx.x;
  const float* src; u16* dst; int K;
  if (bid < 24) { src = w1 + (long)bid*768*64; dst = w1t + (long)bid*64*768; K = 768; }
  else { int t = bid - 24; src = w2 + (long)t*512*64; dst = w2t + (long)t*64*512; K = 512; }
  int kq = blockIdx.y;
  int kstart = kq * (K >> 2), kend = kstart + (K >> 2);

  for (int k0 = kstart; k0 < kend; k0 += 64) {
    __syncthreads();
    #pragma unroll
    for (int i = 0; i < 4; ++i) {
      int kk = i*16 + (tid >> 4);
      int oo = (tid & 15) * 4;
      float4 v = *(const float4*)(src + (long)(k0 + kk)*64 + oo);
      *(float4*)&tile[kk][oo] = v;
    }
    __syncthreads();
    int o = tid >> 2, kp = (tid & 3) * 16;
    bf16x8 r0, r1;
    #pragma unroll
    for (int j = 0; j < 8; ++j) r0[j] = f2bf(tile[kp + j][o]);
    #pragma unroll
    for (int j = 0; j < 8; ++j) r1[j] = f2bf(tile[kp + 8 + j][o]);
    u16* d = dst + (long)o*K + k0 + kp;
    *(bf16x8*)d = r0;
    *(bf16x8*)(d + 8) = r1;
  }
}

// ---------------------------------------------------------------------------
// K3: layer-1 gathered GEMM, bf16 MFMA. BM=64, BN=128, 4 waves.
// Round-12: FLAT 1056-block grid (was dim3(352,1,3): z dispatches serially,
// leaving ~1.4 blocks/CU resident; occupancy 28% with nothing busy). Flat
// x fills ~4 blocks/CU so cross-block overlap hides the staging latency.
// Double-buffered staging + coalesced loads + XCD decode kept.
// ---------------------------------------------------------------------------
__global__ __launch_bounds__(256) void gemm1_mfma(
    const float* __restrict__ emb,
    const u16* __restrict__ w1t,
    const int* __restrict__ rowlist, const int* __restrict__ counts,
    u16* __restrict__ hp1b)
{
  int i   = blockIdx.x;           // 0..1055
  int t   = i / 352;
  int r   = i - t*352;
  int cnt = counts[t];
  int xcd = r & 7;
  int q   = r >> 3;
  int hb  = q & 3;
  int rb  = (q >> 2) * 8 + xcd;
  int r0  = rb * 64;
  if (r0 >= cnt) return;

  __shared__ short aT[2][4*66*8];
  __shared__ short bT[2][4*130*8];
  __shared__ int rowsS[64];

  int tid = threadIdx.x;
  if (tid < 64) {
    int rr = r0 + tid;
    rowsS[tid] = (rr < cnt) ? rowlist[t*NROWS + rr] : -1;
  }
  __syncthreads();

  int ar = tid >> 2, ac = tid & 3;
  int sg = rowsS[ar]; if (sg < 0) sg = rowsS[0];
  const float* aP = emb + (long)sg*768;

  int colb = tid >> 2, off = tid & 3;
  const u16* bP1 = w1t + (((long)t*8 + hb*2 + 0)*64 + colb)*768;
  const u16* bP2 = w1t + (((long)t*8 + hb*2 + 1)*64 + colb)*768;

  int wv = tid >> 6, l = tid & 63;
  int wr = wv >> 1, wc = wv & 1;
  int l15 = l & 15, lg = l >> 4;

  int aw0 = (( (ac>>1)     )*66 + ar)*8 + (ac&1)*4;
  int aw1 = (( 2 + (ac>>1) )*66 + ar)*8 + (ac&1)*4;
  int bw0 = (off*130 + colb     )*8;
  int bw1 = (off*130 + colb + 64)*8;

  f32x4 acc[2][4];
  #pragma unroll
  for (int fr = 0; fr < 2; ++fr)
    #pragma unroll
    for (int cf = 0; cf < 4; ++cf) acc[fr][cf] = (f32x4){0.f,0.f,0.f,0.f};

  float4 ra0 = *(const float4*)(aP + ac*4);
  float4 ra1 = *(const float4*)(aP + 16 + ac*4);
  bf16x8 rb1 = *(const bf16x8*)(bP1 + off*8);
  bf16x8 rb2 = *(const bf16x8*)(bP2 + off*8);
  {
    s16x4 w0, w1;
    w0[0]=f2bf(ra0.x); w0[1]=f2bf(ra0.y); w0[2]=f2bf(ra0.z); w0[3]=f2bf(ra0.w);
    w1[0]=f2bf(ra1.x); w1[1]=f2bf(ra1.y); w1[2]=f2bf(ra1.z); w1[3]=f2bf(ra1.w);
    *(s16x4*)&aT[0][aw0] = w0;
    *(s16x4*)&aT[0][aw1] = w1;
    *(bf16x8*)&bT[0][bw0] = rb1;
    *(bf16x8*)&bT[0][bw1] = rb2;
  }
  __syncthreads();

  int cur = 0;
  for (int k0 = 0; k0 < 768; k0 += 32) {
    bool more = (k0 + 32 < 768);
    if (more) {
      ra0 = *(const float4*)(aP + k0 + 32 + ac*4);
      ra1 = *(const float4*)(aP + k0 + 48 + ac*4);
      rb1 = *(const bf16x8*)(bP1 + k0 + 32 + off*8);
      rb2 = *(const bf16x8*)(bP2 + k0 + 32 + off*8);
    }
    bf16x8 af[2], bfr[4];
    #pragma unroll
    for (int fr = 0; fr < 2; ++fr)
      af[fr] = *(const bf16x8*)&aT[cur][(lg*66 + wr*32 + fr*16 + l15)*8];
    #pragma unroll
    for (int cf = 0; cf < 4; ++cf)
      bfr[cf] = *(const bf16x8*)&bT[cur][(lg*130 + wc*64 + cf*16 + l15)*8];
    #pragma unroll
    for (int fr = 0; fr < 2; ++fr)
      #pragma unroll
      for (int cf = 0; cf < 4; ++cf)
        acc[fr][cf] = __builtin_amdgcn_mfma_f32_16x16x32_bf16(af[fr], bfr[cf], acc[fr][cf], 0, 0, 0);
    if (more) {
      s16x4 w0, w1;
      w0[0]=f2bf(ra0.x); w0[1]=f2bf(ra0.y); w0[2]=f2bf(ra0.z); w0[3]=f2bf(ra0.w);
      w1[0]=f2bf(ra1.x); w1[1]=f2bf(ra1.y); w1[2]=f2bf(ra1.z); w1[3]=f2bf(ra1.w);
      *(s16x4*)&aT[cur^1][aw0] = w0;
      *(s16x4*)&aT[cur^1][aw1] = w1;
      *(bf16x8*)&bT[cur^1][bw0] = rb1;
      *(bf16x8*)&bT[cur^1][bw1] = rb2;
    }
    __syncthreads();
    cur ^= 1;
  }

  #pragma unroll
  for (int fr = 0; fr < 2; ++fr) {
    #pragma unroll
    for (int r4 = 0; r4 < 4; ++r4) {
      int rloc = wr*32 + fr*16 + lg*4 + r4;
      int rg = rowsS[rloc];
      if (rg < 0) continue;
      long obase = ((long)(rg >> 9) * 8) * 32768 + (long)(rg & 511) * 64;
      #pragma unroll
      for (int cf = 0; cf < 4; ++cf) {
        int c = wc*64 + cf*16 + l15;
        hp1b[obase + (long)(hb*2 + (c >> 6))*32768 + (c & 63)] = (u16)f2bf(acc[fr][cf][r4]);
      }
    }
  }
}

// ---------------------------------------------------------------------------
// K5: layer-2 gathered GEMM, bf16 MFMA. Round-12: flat 768-block grid.
// ---------------------------------------------------------------------------
__global__ __launch_bounds__(256) void gemm2_mfma(
    const u16* __restrict__ xbf,
    const u16* __restrict__ w2t,
    const int* __restrict__ rowlist, const int* __restrict__ counts,
    float* __restrict__ hp2)
{
  int i   = blockIdx.x;           // 0..767
  int t   = i >> 8;
  int cnt = counts[t];
  int r0  = (i & 255) * 64;
  if (r0 >= cnt) return;

  __shared__ short aT[4*66*8];
  __shared__ short bT[4*66*8];
  __shared__ int rowsS[64];

  int tid = threadIdx.x;
  if (tid < 64) {
    int rr = r0 + tid;
    rowsS[tid] = (rr < cnt) ? rowlist[t*NROWS + rr] : -1;
  }
  __syncthreads();

  int ar = tid >> 2, ac = tid & 3;
  int sg = rowsS[ar]; if (sg < 0) sg = rowsS[0];
  long apart = ((long)(sg >> 9) * 8) * 32768 + (long)(sg & 511) * 64;

  int colb = tid >> 2, off = tid & 3;
  const u16* bP = w2t + ((long)t*64 + colb)*512;

  int wv = tid >> 6, l = tid & 63;
  int l15 = l & 15, lg = l >> 4;

  f32x4 acc[4];
  #pragma unroll
  for (int cf = 0; cf < 4; ++cf) acc[cf] = (f32x4){0.f,0.f,0.f,0.f};

  int ka0 = ac*8;
  bf16x8 ra = *(const bf16x8*)(xbf + apart + (long)(ka0 >> 6)*32768 + (ka0 & 63));
  bf16x8 rb = *(const bf16x8*)(bP + off*8);

  for (int k0 = 0; k0 < 512; k0 += 32) {
    __syncthreads();
    *(bf16x8*)&aT[(ac*66 + ar)*8]   = ra;
    *(bf16x8*)&bT[(off*66 + colb)*8] = rb;
    __syncthreads();
    if (k0 + 32 < 512) {
      int kn = k0 + 32 + ac*8;
      ra = *(const bf16x8*)(xbf + apart + (long)(kn >> 6)*32768 + (kn & 63));
      rb = *(const bf16x8*)(bP + k0 + 32 + off*8);
    }
    bf16x8 af, bfr[4];
    af = *(const bf16x8*)&aT[(lg*66 + wv*16 + l15)*8];
    #pragma unroll
    for (int cf = 0; cf < 4; ++cf)
      bfr[cf] = *(const bf16x8*)&bT[(lg*66 + cf*16 + l15)*8];
    #pragma unroll
    for (int cf = 0; cf < 4; ++cf)
      acc[cf] = __builtin_amdgcn_mfma_f32_16x16x32_bf16(af, bfr[cf], acc[cf], 0, 0, 0);
  }

  #pragma unroll
  for (int r4 = 0; r4 < 4; ++r4) {
    int rloc = wv*16 + lg*4 + r4;
    int rg = rowsS[rloc];
    if (rg < 0) continue;
    #pragma unroll
    for (int cf = 0; cf < 4; ++cf)
      hp2[(long)rg*64 + cf*16 + l15] = acc[cf][r4];
  }
}

// ---------------------------------------------------------------------------
// K4: GAT layer-1 attention. One 1024-thread block per (b,h).
// Round-12 softmax: PAIRWISE k per lane (k=2*lane, 2*lane+1): one 64-bit
// mask shift yields 2 bits; dst read as float2 HOISTED out of the sup loop;
// one v_cvt_pk_bf16_f32 + one ds_write_b32 replaces 2x f2bf + 2x b16 store.
// ~40% fewer softmax VALU instrs. Round-9 structure otherwise unchanged
// (no-max softmax, unnormalized P, deferred rcp; round-10-style pipelining
// deliberately NOT reintroduced — it regressed).
// ---------------------------------------------------------------------------
__global__ __launch_bounds__(1024) void gat1_attn(
    u16* __restrict__ hp1b, const u64* __restrict__ maskw,
    const float* __restrict__ a_src, const float* __restrict__ a_dst,
    const float* __restrict__ b1)
{
  extern __shared__ char smc[];
  short* hpTf = (short*)smc;                  // [64 koct][66 o][8]  67,584 B
  short* pSf  = (short*)(smc + 67584);        // [64 koct][66 row][8] 67,584 B
  float* srcS = (float*)(smc + 135168);       // [512]
  float* dstS = (float*)(smc + 137216);       // [512]
  float* asS  = (float*)(smc + 139264);       // [64]
  float* adS  = (float*)(smc + 139520);       // [64]
  float* rcpS = (float*)(smc + 139776);       // [64]  end 140,032

  int bh = blockIdx.x;
  int b = bh >> 3, h = bh & 7;
  int tid = threadIdx.x;

  if (tid < 64) asS[tid] = a_src[h*64 + tid];
  else if (tid < 128) adS[tid - 64] = a_dst[h*64 + (tid - 64)];
  __syncthreads();

  // phase 0: load V slice, src/dst dots, scatter V into fragment order
  {
    int m = tid >> 1, half = tid & 1;
    int koct = m >> 3, sub = m & 7;
    const u16* hpRow = hp1b + ((long)bh*NN + m)*64 + half*32;
    float ps = 0.f, pd = 0.f;
    #pragma unroll
    for (int qq = 0; qq < 4; ++qq) {
      bf16x8 hv = *(const bf16x8*)(hpRow + qq*8);
      int o0 = half*32 + qq*8;
      #pragma unroll
      for (int j = 0; j < 8; ++j) {
        float f = bf2f(hv[j]);
        ps += f * asS[o0 + j];
        pd += f * adS[o0 + j];
        hpTf[(koct*66 + o0 + j)*8 + sub] = hv[j];
      }
    }
    ps += __shfl_xor(ps, 1);
    pd += __shfl_xor(pd, 1);
    if ((tid & 1) == 0) { srcS[m] = ps; dstS[m] = pd; }
  }
  __syncthreads();

  int wv = tid >> 6, lane = tid & 63;
  int l15 = lane & 15, lg = lane >> 4;
  int cgl = wv >> 2, nt = wv & 3;
  int o_out = nt*16 + l15;
  float bb  = b1[o_out];

  // hoisted: dst pairs for k = 2*lane, 2*lane+1 (row/sup-invariant)
  float2 dst2[4];
  #pragma unroll
  for (int jj = 0; jj < 4; ++jj)
    dst2[jj] = *(const float2*)&dstS[jj*128 + 2*lane];
  int wsel = lane >> 5;
  unsigned sh = (unsigned)((2*lane) & 63);
  // pSf write slot (u32): koct = jj*16 + (lane>>2), t = 2*(lane&3)
  int pbase = ((lane >> 2)*66)*8 + 2*(lane & 3);

  for (int sup = 0; sup < 8; ++sup) {
    // softmax (no-max, unnormalized, pairwise)
    #pragma unroll
    for (int rr = 0; rr < 4; ++rr) {
      int rloc = wv*4 + rr;
      int row  = sup*64 + rloc;
      float srcv = srcS[row];
      const u64* mrow = maskw + ((long)(b*NN + row))*8;
      float lsum = 0.f;
      #pragma unroll
      for (int jj = 0; jj < 4; ++jj) {
        u64 w = mrow[jj*2 + wsel];
        unsigned bits = (unsigned)(w >> sh) & 3u;
        float s0 = srcv + dst2[jj].x;
        float s1 = srcv + dst2[jj].y;
        float p0 = (bits & 1u) ? __expf(lrelu_f(s0)) : 0.f;
        float p1 = (bits & 2u) ? __expf(lrelu_f(s1)) : 0.f;
        lsum += p0 + p1;
        unsigned pk = cvt_pk_bf16(p0, p1);
        *(unsigned*)&pSf[(jj*16*66)*8 + pbase + rloc*8] = pk;
      }
      #pragma unroll
      for (int mk = 1; mk <= 32; mk <<= 1) lsum += __shfl_xor(lsum, mk);
      if (lane == 0) rcpS[rloc] = 1.f / lsum;
    }
    __syncthreads();

    // PV via MFMA: wave (cgl,nt) -> rows cgl*16.., cols nt*16.., K=512
    f32x4 acc = {0.f, 0.f, 0.f, 0.f};
    #pragma unroll
    for (int ks = 0; ks < 16; ++ks) {
      int koct = ks*4 + lg;
      bf16x8 af = *(const bf16x8*)&pSf [(koct*66 + cgl*16 + l15)*8];
      bf16x8 bf = *(const bf16x8*)&hpTf[(koct*66 + nt*16  + l15)*8];
      acc = __builtin_amdgcn_mfma_f32_16x16x32_bf16(af, bf, acc, 0, 0, 0);
    }
    #pragma unroll
    for (int reg = 0; reg < 4; ++reg) {
      int rloc = cgl*16 + lg*4 + reg;
      int row  = sup*64 + rloc;
      float v = elu_f(acc[reg] * rcpS[rloc] + bb);
      hp1b[((long)bh*NN + row)*64 + o_out] = (u16)f2bf(v);
    }
    __syncthreads();
  }
}

// ---------------------------------------------------------------------------
// K6: GAT layer-2 attention (rows 0,1 only) + ELU + MLP + log_softmax.
// ---------------------------------------------------------------------------
__global__ __launch_bounds__(256) void gat2_final(
    const float* __restrict__ hp2, const u64* __restrict__ maskw,
    const float* __restrict__ a_src2, const float* __restrict__ a_dst2,
    const float* __restrict__ b2,
    const float* __restrict__ fc1_w, const float* __restrict__ fc1_b,
    const float* __restrict__ fc2_w, const float* __restrict__ fc2_b,
    const float* __restrict__ fc3_w, const float* __restrict__ fc3_b,
    float* __restrict__ out)
{
  extern __shared__ float sm[];
  float* hpS  = sm;              // 32768
  float* dstS = hpS + 32768;     // 512
  float* srcS = dstS + 512;      // 512
  float* pS   = srcS + 512;      // 512
  float* redS = pS + 512;        // 256
  float* outS = redS + 256;      // 128
  float* vS   = outS + 128;      // 64
  float* y1S  = vS + 64;         // 192
  float* redM = y1S + 192;       // 8
  float4* hpS4 = (float4*)hpS;

  int b = blockIdx.x;
  int tid = threadIdx.x;
  int og = tid & 15, m16 = tid >> 4;

  for (int it = 0; it < 32; ++it) {
    int fi = it*256 + tid;
    int m = fi >> 4, o4 = fi & 15;
    hpS4[m*16 + o4] = *(const float4*)(hp2 + (long)(b*NN + m)*64 + o4*4);
  }
  __syncthreads();

  float4 as4 = *(const float4*)(a_src2 + og*4);
  float4 ad4 = *(const float4*)(a_dst2 + og*4);
  for (int it = 0; it < 32; ++it) {
    int m = it*16 + m16;
    float4 hv = hpS4[m*16 + og];
    float ls = hv.x*as4.x + hv.y*as4.y + hv.z*as4.z + hv.w*as4.w;
    float ld = hv.x*ad4.x + hv.y*ad4.y + hv.z*ad4.z + hv.w*ad4.w;
    #pragma unroll
    for (int mk = 1; mk <= 8; mk <<= 1) {
      ls += __shfl_xor(ls, mk);
      ld += __shfl_xor(ld, mk);
    }
    if (og == 0) { srcS[m] = ls; dstS[m] = ld; }
  }
  __syncthreads();

  for (int n = 0; n < 2; ++n) {
    float srcv = srcS[n];
    const u64* mrow = maskw + (long)(b*NN + n)*8;
    int m0 = tid, m1 = tid + 256;
    u64 w0 = mrow[m0 >> 6], w1 = mrow[m1 >> 6];
    float s0 = srcv + dstS[m0], s1 = srcv + dstS[m1];
    float e0 = ((w0 >> (m0 & 63)) & 1ull) ? lrelu_f(s0) : -1.0e9f;
    float e1 = ((w1 >> (m1 & 63)) & 1ull) ? lrelu_f(s1) : -1.0e9f;
    float emax = fmaxf(e0, e1);
    #pragma unroll
    for (int mk = 1; mk <= 32; mk <<= 1) emax = fmaxf(emax, __shfl_xor(emax, mk));
    if ((tid & 63) == 0) redM[tid >> 6] = emax;
    __syncthreads();
    emax = fmaxf(fmaxf(redM[0], redM[1]), fmaxf(redM[2], redM[3]));
    float p0 = __expf(e0 - emax), p1 = __expf(e1 - emax);
    pS[m0] = p0; pS[m1] = p1;
    float lsum = p0 + p1;
    #pragma unroll
    for (int mk = 1; mk <= 32; mk <<= 1) lsum += __shfl_xor(lsum, mk);
    if ((tid & 63) == 0) redM[4 + (tid >> 6)] = lsum;
    __syncthreads();
    float rcp = 1.f / (redM[4] + redM[5] + redM[6] + redM[7]);

    float4 acc = make_float4(0.f,0.f,0.f,0.f);
    for (int mm = 0; mm < 32; ++mm) {
      int m = mm*16 + m16;
      float4 hv = hpS4[m*16 + og];
      float p = pS[m];
      acc.x += hv.x*p; acc.y += hv.y*p; acc.z += hv.z*p; acc.w += hv.w*p;
    }
    acc.x += __shfl_xor(acc.x, 16); acc.y += __shfl_xor(acc.y, 16);
    acc.z += __shfl_xor(acc.z, 16); acc.w += __shfl_xor(acc.w, 16);
    acc.x += __shfl_xor(acc.x, 32); acc.y += __shfl_xor(acc.y, 32);
    acc.z += __shfl_xor(acc.z, 32); acc.w += __shfl_xor(acc.w, 32);
    __syncthreads();
    if ((tid & 63) < 16) ((float4*)redS)[(tid >> 6)*16 + (tid & 15)] = acc;
    __syncthreads();
    if (tid < 16) {
      float4 s = make_float4(0.f,0.f,0.f,0.f);
      #pragma unroll
      for (int w = 0; w < 4; ++w) {
        float4 v = ((float4*)redS)[w*16 + tid];
        s.x += v.x; s.y += v.y; s.z += v.z; s.w += v.w;
      }
      float4 bv = *(const float4*)(b2 + tid*4);
      outS[n*64 + tid*4 + 0] = elu_f(s.x*rcp + bv.x);
      outS[n*64 + tid*4 + 1] = elu_f(s.y*rcp + bv.y);
      outS[n*64 + tid*4 + 2] = elu_f(s.z*rcp + bv.z);
      outS[n*64 + tid*4 + 3] = elu_f(s.w*rcp + bv.w);
    }
    __syncthreads();
  }

  if (tid < 64) vS[tid] = outS[tid] * outS[64 + tid];
  __syncthreads();
  if (tid < 192) {
    float a = fc1_b[tid];
    for (int o = 0; o < 64; ++o) a += vS[o]*fc1_w[o*192 + tid];
    y1S[tid] = a > 0.f ? a : 0.f;
  }
  __syncthreads();
  if (tid < 64) {
    float a = fc2_b[tid];
    for (int j = 0; j < 192; ++j) a += y1S[j]*fc2_w[j*64 + tid];
    vS[tid] = a > 0.f ? a : 0.f;
  }
  __syncthreads();
  if (tid == 0) {
    float t0 = fc3_b[0], t1 = fc3_b[1];
    for (int k = 0; k < 64; ++k) {
      float y = vS[k];
      t0 += y*fc3_w[k*2 + 0];
      t1 += y*fc3_w[k*2 + 1];
    }
    float mx = fmaxf(t0, t1);
    float lse = mx + logf(__expf(t0 - mx) + __expf(t1 - mx));
    out[b*2 + 0] = t0 - lse;
    out[b*2 + 1] = t1 - lse;
  }
}

// ---------------------------------------------------------------------------
extern "C" void kernel_launch(void* const* d_in, const int* in_sizes, int n_in,
                              void* d_out, int out_size, void* d_ws, size_t ws_size,
                              hipStream_t stream) {
  const float* emb    = (const float*)d_in[0];
  const int*   adj    = (const int*)d_in[1];
  const float* vt     = (const float*)d_in[2];
  const float* w1     = (const float*)d_in[3];
  const float* a_src1 = (const float*)d_in[4];
  const float* a_dst1 = (const float*)d_in[5];
  const float* b1     = (const float*)d_in[6];
  const float* w2     = (const float*)d_in[7];
  const float* a_src2 = (const float*)d_in[8];
  const float* a_dst2 = (const float*)d_in[9];
  const float* b2     = (const float*)d_in[10];
  const float* fc1_w  = (const float*)d_in[11];
  const float* fc1_b  = (const float*)d_in[12];
  const float* fc2_w  = (const float*)d_in[13];
  const float* fc2_b  = (const float*)d_in[14];
  const float* fc3_w  = (const float*)d_in[15];
  const float* fc3_b  = (const float*)d_in[16];

  char* ws = (char*)d_ws;
  int* counts  = (int*)ws;
  int* rowlist = (int*)(ws + 4096);
  u64* maskw   = (u64*)(ws + 204800);
  u16* w1t     = (u16*)(ws + 1310720);
  u16* w2t     = (u16*)(ws + 3670016);
  u16* hp1b    = (u16*)(ws + 3932160);
  float* hp2   = (float*)(ws + 20709376);

  hipMemsetAsync(counts, 0, 16, stream);
  prep_kernel<<<NROWS/4, 256, 0, stream>>>(adj, maskw);
  rowlist_kernel<<<NROWS/256, 256, 0, stream>>>(vt, rowlist, counts);
  conv_w<<<dim3(27, 4), 256, 0, stream>>>(w1, w2, w1t, w2t);

  gemm1_mfma<<<dim3(1056), 256, 0, stream>>>(emb, w1t, rowlist, counts, hp1b);

  size_t sm1 = 140032;
  gat1_attn<<<BB*NH, 1024, sm1, stream>>>(hp1b, maskw, a_src1, a_dst1, b1);

  gemm2_mfma<<<dim3(768), 256, 0, stream>>>(hp1b, w2t, rowlist, counts, hp2);

  size_t sm2 = (size_t)(32768 + 512 + 512 + 512 + 256 + 128 + 64 + 192 + 8) * 4;
  gat2_final<<<BB, 256, sm2, stream>>>(hp2, maskw, a_src2, a_dst2, b2,
                                       fc1_w, fc1_b, fc2_w, fc2_b, fc3_w, fc3_b,
                                       (float*)d_out);
}